// Round 9
// baseline (439.467 us; speedup 1.0000x reference)
//
#include <hip/hip_runtime.h>
#include <hip/hip_bf16.h>
#include <hip/hip_fp16.h>
#include <type_traits>

#define NNODES 100000
#define NEDGES 800000
#define HIDDIM 128
#define NHEAD 4

// bucket sort parameters
#define EPB 2048                 // edges per chunk-block
#define NBLK 392                 // padded to 8*49 so XCD swizzle is exact; chunk 391 is empty
#define XCDG 49                  // NBLK / 8 — contiguous chunks per XCD
#define BSH 7                    // 128 nodes per bucket
#define NBUCK 782                // ceil(NNODES / 128); last bucket has 32 nodes

typedef _Float16 half8 __attribute__((ext_vector_type(8)));
typedef _Float16 half2t __attribute__((ext_vector_type(2)));
typedef float floatx4 __attribute__((ext_vector_type(4)));

// ---------------- CSR build via bucket counting-sort (no global atomics) ----------------

__global__ __launch_bounds__(256) void bucketA_k(const int* __restrict__ e0,
                                                 const int* __restrict__ e1,
                                                 const int* __restrict__ e2,
                                                 int* __restrict__ counts) {
    __shared__ int hist[NBUCK];
    int l = blockIdx.y;
    const int* dst = ((l == 0) ? e0 : (l == 1) ? e1 : e2) + NEDGES;
    int j = blockIdx.x;
    for (int t = threadIdx.x; t < NBUCK; t += 256) hist[t] = 0;
    __syncthreads();
    int base = j * EPB;
    int lim = min(EPB, NEDGES - base);
    if (lim == EPB) {
        #pragma unroll
        for (int it = 0; it < EPB / 256; it++)
            atomicAdd(&hist[dst[base + it * 256 + threadIdx.x] >> BSH], 1);
    } else {
        for (int i = threadIdx.x; i < lim; i += 256)
            atomicAdd(&hist[dst[base + i] >> BSH], 1);
    }
    __syncthreads();
    int* crow = counts + ((size_t)l * NBLK + j) * NBUCK;
    for (int t = threadIdx.x; t < NBUCK; t += 256) crow[t] = hist[t];
}

__global__ __launch_bounds__(256) void bucketB1_k(int* __restrict__ counts,
                                                  int* __restrict__ bucketTotal) {
    __shared__ int part[4][64];
    int l = blockIdx.y;
    int tid = threadIdx.x;
    int wave = tid >> 6;
    int lane = tid & 63;
    int b = blockIdx.x * 64 + lane;
    bool valid = b < NBUCK;
    const int CQ = NBLK / 4;
    int t0 = wave * CQ, t1 = t0 + CQ;
    int sum = 0;
    if (valid) {
        for (int t = t0; t < t1; t++)
            sum += counts[((size_t)l * NBLK + t) * NBUCK + b];
    }
    part[wave][lane] = sum;
    __syncthreads();
    int off = 0;
    for (int w = 0; w < wave; w++) off += part[w][lane];
    if (valid) {
        int run = off;
        for (int t = t0; t < t1; t++) {
            size_t idx = ((size_t)l * NBLK + t) * NBUCK + b;
            int v = counts[idx];
            counts[idx] = run;
            run += v;
        }
        if (wave == 3) bucketTotal[l * NBUCK + b] = run;
    }
}

__global__ __launch_bounds__(1024) void bucketB2_k(const int* __restrict__ bucketTotal,
                                                   int* __restrict__ ebBase,
                                                   int* __restrict__ csrBase) {
    __shared__ int sd[1024];
    int l = blockIdx.x;
    int t = threadIdx.x;
    int tot = (t < NBUCK) ? bucketTotal[l * NBUCK + t] : 0;
    sd[t] = tot;
    __syncthreads();
    for (int off = 1; off < 1024; off <<= 1) {
        int u = (t >= off) ? sd[t - off] : 0;
        __syncthreads();
        sd[t] += u;
        __syncthreads();
    }
    if (t < NBUCK) ebBase[l * NBUCK + t] = sd[t] - tot;
    __syncthreads();
    int nb = (t == NBUCK - 1) ? (NNODES - (NBUCK - 1) * 128) : 128;
    int v2 = (t < NBUCK) ? (tot + nb) : 0;
    sd[t] = v2;
    __syncthreads();
    for (int off = 1; off < 1024; off <<= 1) {
        int u = (t >= off) ? sd[t - off] : 0;
        __syncthreads();
        sd[t] += u;
        __syncthreads();
    }
    if (t < NBUCK) csrBase[l * NBUCK + t] = sd[t] - v2;
}

__global__ __launch_bounds__(256) void bucketC_k(const int* __restrict__ e0,
                                                 const int* __restrict__ e1,
                                                 const int* __restrict__ e2,
                                                 const int* __restrict__ counts,
                                                 const int* __restrict__ ebBase,
                                                 int* __restrict__ edgeBuf) {
    __shared__ int cur[NBUCK];
    int l = blockIdx.y;
    const int* ei = (l == 0) ? e0 : (l == 1) ? e1 : e2;
    const int* src = ei;
    const int* dst = ei + NEDGES;
    int bx = blockIdx.x;
    int j = (bx & 7) * XCDG + (bx >> 3);
    const int* bs = counts + ((size_t)l * NBLK + j) * NBUCK;
    const int* eb = ebBase + l * NBUCK;
    for (int t = threadIdx.x; t < NBUCK; t += 256) cur[t] = eb[t] + bs[t];
    __syncthreads();
    int base = j * EPB;
    int lim = min(EPB, NEDGES - base);
    int* ebuf = edgeBuf + (size_t)l * NEDGES;
    if (lim == EPB) {
        #pragma unroll
        for (int it = 0; it < EPB / 256; it++) {
            int i = it * 256 + threadIdx.x;
            int d = dst[base + i];
            int s = src[base + i];
            int pos = atomicAdd(&cur[d >> BSH], 1);
            ebuf[pos] = ((d & 127) << 17) | s;
        }
    } else {
        for (int i = threadIdx.x; i < lim; i += 256) {
            int d = dst[base + i];
            int s = src[base + i];
            int pos = atomicAdd(&cur[d >> BSH], 1);
            ebuf[pos] = ((d & 127) << 17) | s;
        }
    }
}

__global__ __launch_bounds__(256) void bucketD_k(const int* __restrict__ edgeBuf,
                                                 const int* __restrict__ bucketTotal,
                                                 const int* __restrict__ ebBase,
                                                 const int* __restrict__ csrBase,
                                                 int* __restrict__ offs,
                                                 int* __restrict__ deg,
                                                 int* __restrict__ srcs) {
    __shared__ int cnt[128];
    __shared__ int offl[128];
    __shared__ int cur[128];
    int b = blockIdx.x, l = blockIdx.y;
    int t = threadIdx.x;
    int nb = (b == NBUCK - 1) ? (NNODES - (NBUCK - 1) * 128) : 128;
    int eb0 = ebBase[l * NBUCK + b];
    int ecnt = bucketTotal[l * NBUCK + b];
    int csr0 = csrBase[l * NBUCK + b];
    const int* ebuf = edgeBuf + (size_t)l * NEDGES;
    int* srcsL = srcs + (size_t)l * (NEDGES + NNODES);
    if (t < 128) cnt[t] = 0;
    __syncthreads();
    for (int i = t; i < ecnt; i += 256)
        atomicAdd(&cnt[ebuf[eb0 + i] >> 17], 1);
    __syncthreads();
    if (t < 128) {
        int lane = t & 63;
        int x = cnt[t] + 1;
        #pragma unroll
        for (int o = 1; o < 64; o <<= 1) {
            int u = __shfl_up(x, o);
            if (lane >= o) x += u;
        }
        offl[t] = x;
    }
    __syncthreads();
    if (t < 128) {
        int c = cnt[t];
        int incl = offl[t] + ((t >= 64) ? offl[63] : 0);
        int o = csr0 + incl - (c + 1);
        cur[t] = o;
        if (t < nb) {
            int node = b * 128 + t;
            offs[l * NNODES + node] = o;
            deg[l * NNODES + node] = c;
            srcsL[o + c] = node;
        }
    }
    __syncthreads();
    for (int i = t; i < ecnt; i += 256) {
        int w = ebuf[eb0 + i];
        int pos = atomicAdd(&cur[w >> 17], 1);
        srcsL[pos] = w & 0x1FFFF;
    }
}

// ---------------- GEMM + attention logits via extended-N MFMA ----------------
// h16[M,128] = fp16(A @ B); aS[M,4]/aD[M,4] = src/dst logits per head.
// (x@W)·att == x·(W@att): appended columns 128..135 hold Wa = W @ att_masked.
// 64 rows/block (grid 1563 vs old 391): 6.1 blocks/CU queued, B fragments read
// from LDS inline (no 144-VGPR bfrag preload) -> 4 blocks/CU resident.

template <typename AT>
__global__ __launch_bounds__(256, 4) void gemm_mfma_k(const AT* __restrict__ A,
                                                      const float* __restrict__ B,
                                                      const float* __restrict__ attS,
                                                      const float* __restrict__ attD,
                                                      __half* __restrict__ C16,
                                                      float* __restrict__ aS,
                                                      float* __restrict__ aD, int M) {
    __shared__ __half Bt[144 * 136];  // Bt[n][k]; rows 128..135 Wa cols, 136..143 zero
    const int tid = threadIdx.x;
    {   // stage B transposed as fp16 (rows 0..127)
        int kk = (tid & 63) * 2;
        int g = tid >> 6;
        #pragma unroll
        for (int jn = 0; jn < 8; jn++) {
            int n0 = g * 4 + jn * 16;
            float4 r0 = *(const float4*)(B + (size_t)kk * 128 + n0);
            float4 r1 = *(const float4*)(B + (size_t)(kk + 1) * 128 + n0);
            float f0[4] = {r0.x, r0.y, r0.z, r0.w};
            float f1[4] = {r1.x, r1.y, r1.z, r1.w};
            #pragma unroll
            for (int i = 0; i < 4; i++)
                *(__half2*)(&Bt[(n0 + i) * 136 + kk]) = __floats2half2_rn(f0[i], f1[i]);
        }
    }
    if (tid < 128) {  // Wa columns (rows 128..135), fp32 accumulate
        int k = tid;
        const float* Brow = B + (size_t)k * 128;
        #pragma unroll
        for (int h = 0; h < NHEAD; h++) {
            float s0 = 0.f, s1 = 0.f;
            #pragma unroll 8
            for (int c = 0; c < 32; c++) {
                float bb = Brow[h * 32 + c];
                s0 += bb * attS[h * 32 + c];
                s1 += bb * attD[h * 32 + c];
            }
            Bt[(128 + h * 2 + 0) * 136 + k] = (_Float16)s0;
            Bt[(128 + h * 2 + 1) * 136 + k] = (_Float16)s1;
        }
    } else {
        int k = tid - 128;
        #pragma unroll
        for (int j = 8; j < 16; j++) Bt[(128 + j) * 136 + k] = (_Float16)0.f;
    }
    __syncthreads();

    const int lane = tid & 63;
    const int wave = tid >> 6;
    const int m = lane & 15;
    const int q = lane >> 4;

    int rb = blockIdx.x * 64 + wave * 16;  // wave-uniform
    if (rb >= M) return;
    int row = rb + m;
    int rowc = row < M ? row : M - 1;
    half8 a[4];
    if constexpr (std::is_same<AT, __half>::value) {
        const __half* ap = A + (size_t)rowc * HIDDIM;
        #pragma unroll
        for (int t = 0; t < 4; t++)
            a[t] = *(const half8*)(ap + t * 32 + q * 8);
    } else {
        const float* ap = A + (size_t)rowc * HIDDIM;
        #pragma unroll
        for (int t = 0; t < 4; t++) {
            float4 u = *(const float4*)(ap + t * 32 + q * 8);
            float4 v = *(const float4*)(ap + t * 32 + q * 8 + 4);
            half8 h;
            h[0] = (_Float16)u.x; h[1] = (_Float16)u.y;
            h[2] = (_Float16)u.z; h[3] = (_Float16)u.w;
            h[4] = (_Float16)v.x; h[5] = (_Float16)v.y;
            h[6] = (_Float16)v.z; h[7] = (_Float16)v.w;
            a[t] = h;
        }
    }
    floatx4 acc[9];
    #pragma unroll
    for (int c = 0; c < 9; c++) acc[c] = (floatx4){0.f, 0.f, 0.f, 0.f};
    #pragma unroll
    for (int t = 0; t < 4; t++)
        #pragma unroll
        for (int c = 0; c < 9; c++) {
            half8 bf = *(const half8*)(&Bt[(c * 16 + m) * 136 + t * 32 + q * 8]);
            acc[c] = __builtin_amdgcn_mfma_f32_16x16x32_f16(a[t], bf, acc[c], 0, 0, 0);
        }
    #pragma unroll
    for (int c = 0; c < 8; c++)
        #pragma unroll
        for (int r = 0; r < 4; r++) {
            int grow = rb + q * 4 + r;
            if (grow < M)
                C16[(size_t)grow * HIDDIM + c * 16 + m] = __float2half(acc[c][r]);
        }
    if (m < 8) {
        float* ap = (m & 1) ? aD : aS;
        int head = m >> 1;
        #pragma unroll
        for (int r = 0; r < 4; r++) {
            int grow = rb + q * 4 + r;
            if (grow < M) ap[(size_t)grow * 4 + head] = acc[8][r];
        }
    }
}

// ---------------- aggregate: one 16-lane group per node, 2x 8-deep gather ----------------

template <bool HALF_OUT>
__global__ __launch_bounds__(256) void agg_k(const __half* __restrict__ h16,
                                             const int* __restrict__ offs,
                                             const int* __restrict__ deg,
                                             const int* __restrict__ srcs,
                                             const float* __restrict__ aS,
                                             const float* __restrict__ aD,
                                             const float* __restrict__ bias,
                                             void* __restrict__ outv) {
    int tid = threadIdx.x;
    int lane = tid & 63;
    int grp = lane >> 4;      // node group within wave (0..3)
    int cg = lane & 15;       // channel group within node
    int c8 = cg * 8;
    int head = cg >> 2;
    int n = blockIdx.x * 16 + (tid >> 6) * 4 + grp;
    bool nvalid = n < NNODES;
    int nn = nvalid ? n : NNODES - 1;
    int start = offs[nn];
    int cnt = deg[nn] + 1;
    float ad = aD[(size_t)nn * 4 + head];
    half2t acc0[4], acc1[4];
    #pragma unroll
    for (int i = 0; i < 4; i++) {
        acc0[i] = (half2t){(_Float16)0.f, (_Float16)0.f};
        acc1[i] = (half2t){(_Float16)0.f, (_Float16)0.f};
    }
    float wsum = 0.f;
    const int base = grp * 16;

    for (int chunk = 0; chunk < cnt; chunk += 16) {
        int idx = chunk + cg;
        int lim = cnt - chunk;  // edges beyond lim get weight 0
        int sv = srcs[start + (idx < cnt ? idx : cnt - 1)];  // clamped: always valid
        #pragma unroll
        for (int hblk = 0; hblk < 2; hblk++) {
            int jb = hblk * 8;
            if (jb >= lim) break;  // uniform within the 16-lane node group
            float asv[8];
            half8 hv[8];
            // issue all 8 edges' gathers up front — 8-deep MLP per lane
            #pragma unroll
            for (int j = 0; j < 8; j++) {
                int sj = __shfl(sv, base + jb + j);
                asv[j] = aS[(size_t)sj * 4 + head];
                hv[j] = *(const half8*)(h16 + (size_t)sj * HIDDIM + c8);
            }
            #pragma unroll
            for (int j = 0; j < 8; j++) {
                float e = asv[j] + ad;
                e = (e > 0.f) ? e : 0.2f * e;
                float w = (jb + j < lim) ? __expf(e) : 0.f;
                wsum += w;
                _Float16 wh = (_Float16)w;
                half2t w2 = (half2t){wh, wh};
                if (((jb + j) & 1) == 0) {
                    #pragma unroll
                    for (int i = 0; i < 4; i++)
                        acc0[i] += w2 * (half2t){hv[j][2 * i], hv[j][2 * i + 1]};
                } else {
                    #pragma unroll
                    for (int i = 0; i < 4; i++)
                        acc1[i] += w2 * (half2t){hv[j][2 * i], hv[j][2 * i + 1]};
                }
            }
        }
    }

    if (nvalid) {
        float inv = 1.f / (wsum + 1e-16f);
        float v[8];
        #pragma unroll
        for (int i = 0; i < 4; i++) {
            half2t s = acc0[i] + acc1[i];
            float o0 = (float)s[0] * inv + bias[c8 + 2 * i];
            float o1 = (float)s[1] * inv + bias[c8 + 2 * i + 1];
            v[2 * i] = o0 > 0.f ? o0 : 0.f;
            v[2 * i + 1] = o1 > 0.f ? o1 : 0.f;
        }
        if constexpr (HALF_OUT) {
            union { uint4 u; __half2 h2v[4]; } pk;
            #pragma unroll
            for (int i = 0; i < 4; i++) pk.h2v[i] = __floats2half2_rn(v[2 * i], v[2 * i + 1]);
            *(uint4*)((__half*)outv + (size_t)n * HIDDIM + c8) = pk.u;
        } else {
            float* out = (float*)outv;
            *(float4*)(out + (size_t)n * HIDDIM + c8) = make_float4(v[0], v[1], v[2], v[3]);
            *(float4*)(out + (size_t)n * HIDDIM + c8 + 4) = make_float4(v[4], v[5], v[6], v[7]);
        }
    }
}

// ---------------- launch ----------------

extern "C" void kernel_launch(void* const* d_in, const int* in_sizes, int n_in,
                              void* d_out, int out_size, void* d_ws, size_t ws_size,
                              hipStream_t stream) {
    (void)in_sizes; (void)n_in; (void)out_size; (void)ws_size;
    const float* x = (const float*)d_in[0];
    const int* e0 = (const int*)d_in[1];
    const int* e1 = (const int*)d_in[6];
    const int* e2 = (const int*)d_in[11];

    char* ws = (char*)d_ws;
    size_t off = 0;
    auto alloc = [&](size_t bytes) -> void* {
        void* p = ws + off;
        off += (bytes + 255) & ~(size_t)255;
        return p;
    };
    __half* xh      = (__half*)alloc((size_t)NNODES * HIDDIM * 2);
    __half* h16     = (__half*)alloc((size_t)NNODES * HIDDIM * 2);
    float* aS       = (float*)alloc((size_t)NNODES * 4 * 4);
    float* aD       = (float*)alloc((size_t)NNODES * 4 * 4);
    int* deg        = (int*)alloc((size_t)3 * NNODES * 4);
    int* offsArr    = (int*)alloc((size_t)3 * NNODES * 4);
    int* srcs       = (int*)alloc((size_t)3 * (NEDGES + NNODES) * 4);
    int* counts     = (int*)alloc((size_t)3 * NBLK * NBUCK * 4);
    int* bucketTot  = (int*)alloc((size_t)3 * NBUCK * 4);
    int* ebBase     = (int*)alloc((size_t)3 * NBUCK * 4);
    int* csrBase    = (int*)alloc((size_t)3 * NBUCK * 4);
    int* edgeBuf    = (int*)alloc((size_t)3 * NEDGES * 4);

    // CSR build for all 3 layers — no global atomics
    hipLaunchKernelGGL(bucketA_k, dim3(NBLK, 3), dim3(256), 0, stream, e0, e1, e2, counts);
    hipLaunchKernelGGL(bucketB1_k, dim3((NBUCK + 63) / 64, 3), dim3(256), 0, stream,
                       counts, bucketTot);
    hipLaunchKernelGGL(bucketB2_k, dim3(3), dim3(1024), 0, stream, bucketTot, ebBase, csrBase);
    hipLaunchKernelGGL(bucketC_k, dim3(NBLK, 3), dim3(256), 0, stream,
                       e0, e1, e2, counts, ebBase, edgeBuf);
    hipLaunchKernelGGL(bucketD_k, dim3(NBUCK, 3), dim3(256), 0, stream,
                       edgeBuf, bucketTot, ebBase, csrBase, offsArr, deg, srcs);

    for (int l = 0; l < 3; l++) {
        const float* Wm    = (const float*)d_in[2 + 5 * l];
        const float* attS  = (const float*)d_in[3 + 5 * l];
        const float* attD  = (const float*)d_in[4 + 5 * l];
        const float* biasv = (const float*)d_in[5 + 5 * l];
        const int* offsL = offsArr + l * NNODES;
        const int* degL  = deg + l * NNODES;
        const int* srcsL = srcs + (size_t)l * (NEDGES + NNODES);

        if (l == 0) {
            hipLaunchKernelGGL((gemm_mfma_k<float>), dim3((NNODES + 63) / 64), dim3(256), 0,
                               stream, x, Wm, attS, attD, h16, aS, aD, NNODES);
        } else {
            hipLaunchKernelGGL((gemm_mfma_k<__half>), dim3((NNODES + 63) / 64), dim3(256), 0,
                               stream, xh, Wm, attS, attD, h16, aS, aD, NNODES);
        }
        if (l == 2) {
            hipLaunchKernelGGL((agg_k<false>), dim3((NNODES + 15) / 16), dim3(256), 0, stream,
                               h16, offsL, degL, srcsL, aS, aD, biasv, d_out);
        } else {
            hipLaunchKernelGGL((agg_k<true>), dim3((NNODES + 15) / 16), dim3(256), 0, stream,
                               h16, offsL, degL, srcsL, aS, aD, biasv, (void*)xh);
        }
    }
}

// Round 11
// 409.446 us; speedup vs baseline: 1.0733x; 1.0733x over previous
//
#include <hip/hip_runtime.h>
#include <hip/hip_bf16.h>
#include <hip/hip_fp16.h>
#include <type_traits>

#define NNODES 100000
#define NEDGES 800000
#define HIDDIM 128
#define NHEAD 4

// bucket sort parameters
#define EPB 2048                 // edges per chunk-block
#define NBLK 392                 // padded to 8*49 so XCD swizzle is exact; chunk 391 is empty
#define XCDG 49                  // NBLK / 8 — contiguous chunks per XCD
#define BSH 7                    // 128 nodes per bucket
#define NBUCK 782                // ceil(NNODES / 128); last bucket has 32 nodes

typedef _Float16 half8 __attribute__((ext_vector_type(8)));
typedef _Float16 half2t __attribute__((ext_vector_type(2)));
typedef float floatx4 __attribute__((ext_vector_type(4)));

// ---------------- CSR build via bucket counting-sort (no global atomics) ----------------

__global__ __launch_bounds__(256) void bucketA_k(const int* __restrict__ e0,
                                                 const int* __restrict__ e1,
                                                 const int* __restrict__ e2,
                                                 int* __restrict__ counts) {
    __shared__ int hist[NBUCK];
    int l = blockIdx.y;
    const int* dst = ((l == 0) ? e0 : (l == 1) ? e1 : e2) + NEDGES;
    int j = blockIdx.x;
    for (int t = threadIdx.x; t < NBUCK; t += 256) hist[t] = 0;
    __syncthreads();
    int base = j * EPB;
    int lim = min(EPB, NEDGES - base);
    if (lim == EPB) {
        #pragma unroll
        for (int it = 0; it < EPB / 256; it++)
            atomicAdd(&hist[dst[base + it * 256 + threadIdx.x] >> BSH], 1);
    } else {
        for (int i = threadIdx.x; i < lim; i += 256)
            atomicAdd(&hist[dst[base + i] >> BSH], 1);
    }
    __syncthreads();
    int* crow = counts + ((size_t)l * NBLK + j) * NBUCK;
    for (int t = threadIdx.x; t < NBUCK; t += 256) crow[t] = hist[t];
}

__global__ __launch_bounds__(256) void bucketB1_k(int* __restrict__ counts,
                                                  int* __restrict__ bucketTotal) {
    __shared__ int part[4][64];
    int l = blockIdx.y;
    int tid = threadIdx.x;
    int wave = tid >> 6;
    int lane = tid & 63;
    int b = blockIdx.x * 64 + lane;
    bool valid = b < NBUCK;
    const int CQ = NBLK / 4;
    int t0 = wave * CQ, t1 = t0 + CQ;
    int sum = 0;
    if (valid) {
        for (int t = t0; t < t1; t++)
            sum += counts[((size_t)l * NBLK + t) * NBUCK + b];
    }
    part[wave][lane] = sum;
    __syncthreads();
    int off = 0;
    for (int w = 0; w < wave; w++) off += part[w][lane];
    if (valid) {
        int run = off;
        for (int t = t0; t < t1; t++) {
            size_t idx = ((size_t)l * NBLK + t) * NBUCK + b;
            int v = counts[idx];
            counts[idx] = run;
            run += v;
        }
        if (wave == 3) bucketTotal[l * NBUCK + b] = run;
    }
}

__global__ __launch_bounds__(1024) void bucketB2_k(const int* __restrict__ bucketTotal,
                                                   int* __restrict__ ebBase,
                                                   int* __restrict__ csrBase) {
    __shared__ int sd[1024];
    int l = blockIdx.x;
    int t = threadIdx.x;
    int tot = (t < NBUCK) ? bucketTotal[l * NBUCK + t] : 0;
    sd[t] = tot;
    __syncthreads();
    for (int off = 1; off < 1024; off <<= 1) {
        int u = (t >= off) ? sd[t - off] : 0;
        __syncthreads();
        sd[t] += u;
        __syncthreads();
    }
    if (t < NBUCK) ebBase[l * NBUCK + t] = sd[t] - tot;
    __syncthreads();
    int nb = (t == NBUCK - 1) ? (NNODES - (NBUCK - 1) * 128) : 128;
    int v2 = (t < NBUCK) ? (tot + nb) : 0;
    sd[t] = v2;
    __syncthreads();
    for (int off = 1; off < 1024; off <<= 1) {
        int u = (t >= off) ? sd[t - off] : 0;
        __syncthreads();
        sd[t] += u;
        __syncthreads();
    }
    if (t < NBUCK) csrBase[l * NBUCK + t] = sd[t] - v2;
}

__global__ __launch_bounds__(256) void bucketC_k(const int* __restrict__ e0,
                                                 const int* __restrict__ e1,
                                                 const int* __restrict__ e2,
                                                 const int* __restrict__ counts,
                                                 const int* __restrict__ ebBase,
                                                 int* __restrict__ edgeBuf) {
    __shared__ int cur[NBUCK];
    int l = blockIdx.y;
    const int* ei = (l == 0) ? e0 : (l == 1) ? e1 : e2;
    const int* src = ei;
    const int* dst = ei + NEDGES;
    int bx = blockIdx.x;
    int j = (bx & 7) * XCDG + (bx >> 3);
    const int* bs = counts + ((size_t)l * NBLK + j) * NBUCK;
    const int* eb = ebBase + l * NBUCK;
    for (int t = threadIdx.x; t < NBUCK; t += 256) cur[t] = eb[t] + bs[t];
    __syncthreads();
    int base = j * EPB;
    int lim = min(EPB, NEDGES - base);
    int* ebuf = edgeBuf + (size_t)l * NEDGES;
    if (lim == EPB) {
        #pragma unroll
        for (int it = 0; it < EPB / 256; it++) {
            int i = it * 256 + threadIdx.x;
            int d = dst[base + i];
            int s = src[base + i];
            int pos = atomicAdd(&cur[d >> BSH], 1);
            ebuf[pos] = ((d & 127) << 17) | s;
        }
    } else {
        for (int i = threadIdx.x; i < lim; i += 256) {
            int d = dst[base + i];
            int s = src[base + i];
            int pos = atomicAdd(&cur[d >> BSH], 1);
            ebuf[pos] = ((d & 127) << 17) | s;
        }
    }
}

__global__ __launch_bounds__(256) void bucketD_k(const int* __restrict__ edgeBuf,
                                                 const int* __restrict__ bucketTotal,
                                                 const int* __restrict__ ebBase,
                                                 const int* __restrict__ csrBase,
                                                 int* __restrict__ offs,
                                                 int* __restrict__ deg,
                                                 int* __restrict__ srcs) {
    __shared__ int cnt[128];
    __shared__ int offl[128];
    __shared__ int cur[128];
    int b = blockIdx.x, l = blockIdx.y;
    int t = threadIdx.x;
    int nb = (b == NBUCK - 1) ? (NNODES - (NBUCK - 1) * 128) : 128;
    int eb0 = ebBase[l * NBUCK + b];
    int ecnt = bucketTotal[l * NBUCK + b];
    int csr0 = csrBase[l * NBUCK + b];
    const int* ebuf = edgeBuf + (size_t)l * NEDGES;
    int* srcsL = srcs + (size_t)l * (NEDGES + NNODES);
    if (t < 128) cnt[t] = 0;
    __syncthreads();
    for (int i = t; i < ecnt; i += 256)
        atomicAdd(&cnt[ebuf[eb0 + i] >> 17], 1);
    __syncthreads();
    if (t < 128) {
        int lane = t & 63;
        int x = cnt[t] + 1;
        #pragma unroll
        for (int o = 1; o < 64; o <<= 1) {
            int u = __shfl_up(x, o);
            if (lane >= o) x += u;
        }
        offl[t] = x;
    }
    __syncthreads();
    if (t < 128) {
        int c = cnt[t];
        int incl = offl[t] + ((t >= 64) ? offl[63] : 0);
        int o = csr0 + incl - (c + 1);
        cur[t] = o;
        if (t < nb) {
            int node = b * 128 + t;
            offs[l * NNODES + node] = o;
            deg[l * NNODES + node] = c;
            srcsL[o + c] = node;
        }
    }
    __syncthreads();
    for (int i = t; i < ecnt; i += 256) {
        int w = ebuf[eb0 + i];
        int pos = atomicAdd(&cur[w >> 17], 1);
        srcsL[pos] = w & 0x1FFFF;
    }
}

// ---------------- GEMM + attention logits via extended-N MFMA ----------------
// h16[M,128] = fp16(A @ B); aS[M,4]/aD[M,4] = src/dst logits per head.
// (x@W)·att == x·(W@att): appended columns 128..135 hold Wa = W @ att_masked.
// r8 structure (bfrag register preload, amortized LDS reads) at 128 rows/block:
// grid 782 (~3 blocks/CU queued, 2 resident) so one block's staging/preload
// overlaps another's compute. r9's inline-LDS variant regressed (900K bank
// conflicts, 4x staging replication) — do not remove the preload.

template <typename AT>
__global__ __launch_bounds__(256, 2) void gemm_mfma_k(const AT* __restrict__ A,
                                                      const float* __restrict__ B,
                                                      const float* __restrict__ attS,
                                                      const float* __restrict__ attD,
                                                      __half* __restrict__ C16,
                                                      float* __restrict__ aS,
                                                      float* __restrict__ aD, int M) {
    __shared__ __half Bt[144 * 136];  // Bt[n][k]; rows 128..135 Wa cols, 136..143 zero
    const int tid = threadIdx.x;
    {   // stage B transposed as fp16 (rows 0..127)
        int kk = (tid & 63) * 2;
        int g = tid >> 6;
        #pragma unroll
        for (int jn = 0; jn < 8; jn++) {
            int n0 = g * 4 + jn * 16;
            float4 r0 = *(const float4*)(B + (size_t)kk * 128 + n0);
            float4 r1 = *(const float4*)(B + (size_t)(kk + 1) * 128 + n0);
            float f0[4] = {r0.x, r0.y, r0.z, r0.w};
            float f1[4] = {r1.x, r1.y, r1.z, r1.w};
            #pragma unroll
            for (int i = 0; i < 4; i++)
                *(__half2*)(&Bt[(n0 + i) * 136 + kk]) = __floats2half2_rn(f0[i], f1[i]);
        }
    }
    if (tid < 128) {  // Wa columns (rows 128..135), fp32 accumulate
        int k = tid;
        const float* Brow = B + (size_t)k * 128;
        #pragma unroll
        for (int h = 0; h < NHEAD; h++) {
            float s0 = 0.f, s1 = 0.f;
            #pragma unroll 8
            for (int c = 0; c < 32; c++) {
                float bb = Brow[h * 32 + c];
                s0 += bb * attS[h * 32 + c];
                s1 += bb * attD[h * 32 + c];
            }
            Bt[(128 + h * 2 + 0) * 136 + k] = (_Float16)s0;
            Bt[(128 + h * 2 + 1) * 136 + k] = (_Float16)s1;
        }
    } else {
        int k = tid - 128;
        #pragma unroll
        for (int j = 8; j < 16; j++) Bt[(128 + j) * 136 + k] = (_Float16)0.f;
    }
    __syncthreads();

    const int lane = tid & 63;
    const int wave = tid >> 6;
    const int m = lane & 15;
    const int q = lane >> 4;

    half8 bfrag[9][4];
    #pragma unroll
    for (int c = 0; c < 9; c++)
        #pragma unroll
        for (int t = 0; t < 4; t++)
            bfrag[c][t] = *(const half8*)(&Bt[(c * 16 + m) * 136 + t * 32 + q * 8]);

    for (int iter = 0; iter < 2; iter++) {
        int rb = blockIdx.x * 128 + iter * 64 + wave * 16;  // wave-uniform
        if (rb >= M) break;
        int row = rb + m;
        int rowc = row < M ? row : M - 1;
        half8 a[4];
        if constexpr (std::is_same<AT, __half>::value) {
            const __half* ap = A + (size_t)rowc * HIDDIM;
            #pragma unroll
            for (int t = 0; t < 4; t++)
                a[t] = *(const half8*)(ap + t * 32 + q * 8);
        } else {
            const float* ap = A + (size_t)rowc * HIDDIM;
            #pragma unroll
            for (int t = 0; t < 4; t++) {
                float4 u = *(const float4*)(ap + t * 32 + q * 8);
                float4 v = *(const float4*)(ap + t * 32 + q * 8 + 4);
                half8 h;
                h[0] = (_Float16)u.x; h[1] = (_Float16)u.y;
                h[2] = (_Float16)u.z; h[3] = (_Float16)u.w;
                h[4] = (_Float16)v.x; h[5] = (_Float16)v.y;
                h[6] = (_Float16)v.z; h[7] = (_Float16)v.w;
                a[t] = h;
            }
        }
        floatx4 acc[9];
        #pragma unroll
        for (int c = 0; c < 9; c++) acc[c] = (floatx4){0.f, 0.f, 0.f, 0.f};
        #pragma unroll
        for (int t = 0; t < 4; t++)
            #pragma unroll
            for (int c = 0; c < 9; c++)
                acc[c] = __builtin_amdgcn_mfma_f32_16x16x32_f16(a[t], bfrag[c][t], acc[c], 0, 0, 0);
        #pragma unroll
        for (int c = 0; c < 8; c++)
            #pragma unroll
            for (int r = 0; r < 4; r++) {
                int grow = rb + q * 4 + r;
                if (grow < M)
                    C16[(size_t)grow * HIDDIM + c * 16 + m] = __float2half(acc[c][r]);
            }
        if (m < 8) {
            float* ap = (m & 1) ? aD : aS;
            int head = m >> 1;
            #pragma unroll
            for (int r = 0; r < 4; r++) {
                int grow = rb + q * 4 + r;
                if (grow < M) ap[(size_t)grow * 4 + head] = acc[8][r];
            }
        }
    }
}

// ---------------- aggregate: one 16-lane group per node, 2x 8-deep gather ----------------

template <bool HALF_OUT>
__global__ __launch_bounds__(256) void agg_k(const __half* __restrict__ h16,
                                             const int* __restrict__ offs,
                                             const int* __restrict__ deg,
                                             const int* __restrict__ srcs,
                                             const float* __restrict__ aS,
                                             const float* __restrict__ aD,
                                             const float* __restrict__ bias,
                                             void* __restrict__ outv) {
    int tid = threadIdx.x;
    int lane = tid & 63;
    int grp = lane >> 4;      // node group within wave (0..3)
    int cg = lane & 15;       // channel group within node
    int c8 = cg * 8;
    int head = cg >> 2;
    int n = blockIdx.x * 16 + (tid >> 6) * 4 + grp;
    bool nvalid = n < NNODES;
    int nn = nvalid ? n : NNODES - 1;
    int start = offs[nn];
    int cnt = deg[nn] + 1;
    float ad = aD[(size_t)nn * 4 + head];
    half2t acc0[4], acc1[4];
    #pragma unroll
    for (int i = 0; i < 4; i++) {
        acc0[i] = (half2t){(_Float16)0.f, (_Float16)0.f};
        acc1[i] = (half2t){(_Float16)0.f, (_Float16)0.f};
    }
    float wsum = 0.f;
    const int base = grp * 16;

    for (int chunk = 0; chunk < cnt; chunk += 16) {
        int idx = chunk + cg;
        int lim = cnt - chunk;  // edges beyond lim get weight 0
        int sv = srcs[start + (idx < cnt ? idx : cnt - 1)];  // clamped: always valid
        #pragma unroll
        for (int hblk = 0; hblk < 2; hblk++) {
            int jb = hblk * 8;
            if (jb >= lim) break;  // uniform within the 16-lane node group
            float asv[8];
            half8 hv[8];
            // issue all 8 edges' gathers up front — 8-deep MLP per lane
            #pragma unroll
            for (int j = 0; j < 8; j++) {
                int sj = __shfl(sv, base + jb + j);
                asv[j] = aS[(size_t)sj * 4 + head];
                hv[j] = *(const half8*)(h16 + (size_t)sj * HIDDIM + c8);
            }
            #pragma unroll
            for (int j = 0; j < 8; j++) {
                float e = asv[j] + ad;
                e = (e > 0.f) ? e : 0.2f * e;
                float w = (jb + j < lim) ? __expf(e) : 0.f;
                wsum += w;
                _Float16 wh = (_Float16)w;
                half2t w2 = (half2t){wh, wh};
                if (((jb + j) & 1) == 0) {
                    #pragma unroll
                    for (int i = 0; i < 4; i++)
                        acc0[i] += w2 * (half2t){hv[j][2 * i], hv[j][2 * i + 1]};
                } else {
                    #pragma unroll
                    for (int i = 0; i < 4; i++)
                        acc1[i] += w2 * (half2t){hv[j][2 * i], hv[j][2 * i + 1]};
                }
            }
        }
    }

    if (nvalid) {
        float inv = 1.f / (wsum + 1e-16f);
        float v[8];
        #pragma unroll
        for (int i = 0; i < 4; i++) {
            half2t s = acc0[i] + acc1[i];
            float o0 = (float)s[0] * inv + bias[c8 + 2 * i];
            float o1 = (float)s[1] * inv + bias[c8 + 2 * i + 1];
            v[2 * i] = o0 > 0.f ? o0 : 0.f;
            v[2 * i + 1] = o1 > 0.f ? o1 : 0.f;
        }
        if constexpr (HALF_OUT) {
            union { uint4 u; __half2 h2v[4]; } pk;
            #pragma unroll
            for (int i = 0; i < 4; i++) pk.h2v[i] = __floats2half2_rn(v[2 * i], v[2 * i + 1]);
            *(uint4*)((__half*)outv + (size_t)n * HIDDIM + c8) = pk.u;
        } else {
            float* out = (float*)outv;
            *(float4*)(out + (size_t)n * HIDDIM + c8) = make_float4(v[0], v[1], v[2], v[3]);
            *(float4*)(out + (size_t)n * HIDDIM + c8 + 4) = make_float4(v[4], v[5], v[6], v[7]);
        }
    }
}

// ---------------- launch ----------------

extern "C" void kernel_launch(void* const* d_in, const int* in_sizes, int n_in,
                              void* d_out, int out_size, void* d_ws, size_t ws_size,
                              hipStream_t stream) {
    (void)in_sizes; (void)n_in; (void)out_size; (void)ws_size;
    const float* x = (const float*)d_in[0];
    const int* e0 = (const int*)d_in[1];
    const int* e1 = (const int*)d_in[6];
    const int* e2 = (const int*)d_in[11];

    char* ws = (char*)d_ws;
    size_t off = 0;
    auto alloc = [&](size_t bytes) -> void* {
        void* p = ws + off;
        off += (bytes + 255) & ~(size_t)255;
        return p;
    };
    __half* xh      = (__half*)alloc((size_t)NNODES * HIDDIM * 2);
    __half* h16     = (__half*)alloc((size_t)NNODES * HIDDIM * 2);
    float* aS       = (float*)alloc((size_t)NNODES * 4 * 4);
    float* aD       = (float*)alloc((size_t)NNODES * 4 * 4);
    int* deg        = (int*)alloc((size_t)3 * NNODES * 4);
    int* offsArr    = (int*)alloc((size_t)3 * NNODES * 4);
    int* srcs       = (int*)alloc((size_t)3 * (NEDGES + NNODES) * 4);
    int* counts     = (int*)alloc((size_t)3 * NBLK * NBUCK * 4);
    int* bucketTot  = (int*)alloc((size_t)3 * NBUCK * 4);
    int* ebBase     = (int*)alloc((size_t)3 * NBUCK * 4);
    int* csrBase    = (int*)alloc((size_t)3 * NBUCK * 4);
    int* edgeBuf    = (int*)alloc((size_t)3 * NEDGES * 4);

    // CSR build for all 3 layers — no global atomics
    hipLaunchKernelGGL(bucketA_k, dim3(NBLK, 3), dim3(256), 0, stream, e0, e1, e2, counts);
    hipLaunchKernelGGL(bucketB1_k, dim3((NBUCK + 63) / 64, 3), dim3(256), 0, stream,
                       counts, bucketTot);
    hipLaunchKernelGGL(bucketB2_k, dim3(3), dim3(1024), 0, stream, bucketTot, ebBase, csrBase);
    hipLaunchKernelGGL(bucketC_k, dim3(NBLK, 3), dim3(256), 0, stream,
                       e0, e1, e2, counts, ebBase, edgeBuf);
    hipLaunchKernelGGL(bucketD_k, dim3(NBUCK, 3), dim3(256), 0, stream,
                       edgeBuf, bucketTot, ebBase, csrBase, offsArr, deg, srcs);

    for (int l = 0; l < 3; l++) {
        const float* Wm    = (const float*)d_in[2 + 5 * l];
        const float* attS  = (const float*)d_in[3 + 5 * l];
        const float* attD  = (const float*)d_in[4 + 5 * l];
        const float* biasv = (const float*)d_in[5 + 5 * l];
        const int* offsL = offsArr + l * NNODES;
        const int* degL  = deg + l * NNODES;
        const int* srcsL = srcs + (size_t)l * (NEDGES + NNODES);

        if (l == 0) {
            hipLaunchKernelGGL((gemm_mfma_k<float>), dim3((NNODES + 127) / 128), dim3(256), 0,
                               stream, x, Wm, attS, attD, h16, aS, aD, NNODES);
        } else {
            hipLaunchKernelGGL((gemm_mfma_k<__half>), dim3((NNODES + 127) / 128), dim3(256), 0,
                               stream, xh, Wm, attS, attD, h16, aS, aD, NNODES);
        }
        if (l == 2) {
            hipLaunchKernelGGL((agg_k<false>), dim3((NNODES + 15) / 16), dim3(256), 0, stream,
                               h16, offsL, degL, srcsL, aS, aD, biasv, d_out);
        } else {
            hipLaunchKernelGGL((agg_k<true>), dim3((NNODES + 15) / 16), dim3(256), 0, stream,
                               h16, offsL, degL, srcsL, aS, aD, biasv, (void*)xh);
        }
    }
}

// Round 12
// 388.204 us; speedup vs baseline: 1.1321x; 1.0547x over previous
//
#include <hip/hip_runtime.h>
#include <hip/hip_bf16.h>
#include <hip/hip_fp16.h>
#include <type_traits>

#define NNODES 100000
#define NEDGES 800000
#define HIDDIM 128
#define NHEAD 4

// bucket sort parameters
#define EPB 2048                 // edges per chunk-block
#define NBLK 392                 // padded to 8*49 so XCD swizzle is exact; chunk 391 is empty
#define XCDG 49                  // NBLK / 8 — contiguous chunks per XCD
#define BSH 7                    // 128 nodes per bucket
#define NBUCK 782                // ceil(NNODES / 128); last bucket has 32 nodes

typedef _Float16 half8 __attribute__((ext_vector_type(8)));
typedef _Float16 half2t __attribute__((ext_vector_type(2)));
typedef float floatx4 __attribute__((ext_vector_type(4)));

// ---------------- CSR build via bucket counting-sort (no global atomics) ----------------

__global__ __launch_bounds__(256) void bucketA_k(const int* __restrict__ e0,
                                                 const int* __restrict__ e1,
                                                 const int* __restrict__ e2,
                                                 int* __restrict__ counts) {
    __shared__ int hist[NBUCK];
    int l = blockIdx.y;
    const int* dst = ((l == 0) ? e0 : (l == 1) ? e1 : e2) + NEDGES;
    int j = blockIdx.x;
    for (int t = threadIdx.x; t < NBUCK; t += 256) hist[t] = 0;
    __syncthreads();
    int base = j * EPB;
    int lim = min(EPB, NEDGES - base);
    if (lim == EPB) {
        #pragma unroll
        for (int it = 0; it < EPB / 256; it++)
            atomicAdd(&hist[dst[base + it * 256 + threadIdx.x] >> BSH], 1);
    } else {
        for (int i = threadIdx.x; i < lim; i += 256)
            atomicAdd(&hist[dst[base + i] >> BSH], 1);
    }
    __syncthreads();
    int* crow = counts + ((size_t)l * NBLK + j) * NBUCK;
    for (int t = threadIdx.x; t < NBUCK; t += 256) crow[t] = hist[t];
}

__global__ __launch_bounds__(256) void bucketB1_k(int* __restrict__ counts,
                                                  int* __restrict__ bucketTotal) {
    __shared__ int part[4][64];
    int l = blockIdx.y;
    int tid = threadIdx.x;
    int wave = tid >> 6;
    int lane = tid & 63;
    int b = blockIdx.x * 64 + lane;
    bool valid = b < NBUCK;
    const int CQ = NBLK / 4;
    int t0 = wave * CQ, t1 = t0 + CQ;
    int sum = 0;
    if (valid) {
        for (int t = t0; t < t1; t++)
            sum += counts[((size_t)l * NBLK + t) * NBUCK + b];
    }
    part[wave][lane] = sum;
    __syncthreads();
    int off = 0;
    for (int w = 0; w < wave; w++) off += part[w][lane];
    if (valid) {
        int run = off;
        for (int t = t0; t < t1; t++) {
            size_t idx = ((size_t)l * NBLK + t) * NBUCK + b;
            int v = counts[idx];
            counts[idx] = run;
            run += v;
        }
        if (wave == 3) bucketTotal[l * NBUCK + b] = run;
    }
}

__global__ __launch_bounds__(1024) void bucketB2_k(const int* __restrict__ bucketTotal,
                                                   int* __restrict__ ebBase,
                                                   int* __restrict__ csrBase) {
    __shared__ int sd[1024];
    int l = blockIdx.x;
    int t = threadIdx.x;
    int tot = (t < NBUCK) ? bucketTotal[l * NBUCK + t] : 0;
    sd[t] = tot;
    __syncthreads();
    for (int off = 1; off < 1024; off <<= 1) {
        int u = (t >= off) ? sd[t - off] : 0;
        __syncthreads();
        sd[t] += u;
        __syncthreads();
    }
    if (t < NBUCK) ebBase[l * NBUCK + t] = sd[t] - tot;
    __syncthreads();
    int nb = (t == NBUCK - 1) ? (NNODES - (NBUCK - 1) * 128) : 128;
    int v2 = (t < NBUCK) ? (tot + nb) : 0;
    sd[t] = v2;
    __syncthreads();
    for (int off = 1; off < 1024; off <<= 1) {
        int u = (t >= off) ? sd[t - off] : 0;
        __syncthreads();
        sd[t] += u;
        __syncthreads();
    }
    if (t < NBUCK) csrBase[l * NBUCK + t] = sd[t] - v2;
}

__global__ __launch_bounds__(256) void bucketC_k(const int* __restrict__ e0,
                                                 const int* __restrict__ e1,
                                                 const int* __restrict__ e2,
                                                 const int* __restrict__ counts,
                                                 const int* __restrict__ ebBase,
                                                 int* __restrict__ edgeBuf) {
    __shared__ int cur[NBUCK];
    int l = blockIdx.y;
    const int* ei = (l == 0) ? e0 : (l == 1) ? e1 : e2;
    const int* src = ei;
    const int* dst = ei + NEDGES;
    int bx = blockIdx.x;
    int j = (bx & 7) * XCDG + (bx >> 3);
    const int* bs = counts + ((size_t)l * NBLK + j) * NBUCK;
    const int* eb = ebBase + l * NBUCK;
    for (int t = threadIdx.x; t < NBUCK; t += 256) cur[t] = eb[t] + bs[t];
    __syncthreads();
    int base = j * EPB;
    int lim = min(EPB, NEDGES - base);
    int* ebuf = edgeBuf + (size_t)l * NEDGES;
    if (lim == EPB) {
        #pragma unroll
        for (int it = 0; it < EPB / 256; it++) {
            int i = it * 256 + threadIdx.x;
            int d = dst[base + i];
            int s = src[base + i];
            int pos = atomicAdd(&cur[d >> BSH], 1);
            ebuf[pos] = ((d & 127) << 17) | s;
        }
    } else {
        for (int i = threadIdx.x; i < lim; i += 256) {
            int d = dst[base + i];
            int s = src[base + i];
            int pos = atomicAdd(&cur[d >> BSH], 1);
            ebuf[pos] = ((d & 127) << 17) | s;
        }
    }
}

// Phase D: per-bucket CSR finalize. Layer-0 blocks also convert x -> fp16
// (coalesced, overlapped with the latency-bound LDS-atomic scatter) so ALL
// gemm layers read fp16 input (saves 25.6 MB fp32 re-read in layer-0 gemm).
// Rounding is RN, identical to the old in-gemm per-element cast.
__global__ __launch_bounds__(256) void bucketD_k(const int* __restrict__ edgeBuf,
                                                 const int* __restrict__ bucketTotal,
                                                 const int* __restrict__ ebBase,
                                                 const int* __restrict__ csrBase,
                                                 int* __restrict__ offs,
                                                 int* __restrict__ deg,
                                                 int* __restrict__ srcs,
                                                 const float* __restrict__ x,
                                                 __half* __restrict__ xh) {
    __shared__ int cnt[128];
    __shared__ int offl[128];
    __shared__ int cur[128];
    int b = blockIdx.x, l = blockIdx.y;
    int t = threadIdx.x;

    if (l == 0) {
        // fused x -> fp16 conversion: 16384 elems/block, float4x2 -> uint4
        const size_t T = (size_t)NNODES * HIDDIM;  // 12.8M, multiple of 8
        size_t base = (size_t)b * 16384;
        #pragma unroll
        for (int i = 0; i < 8; i++) {
            size_t e8 = base + ((size_t)i * 256 + t) * 8;
            if (e8 < T) {
                float4 u = *(const float4*)(x + e8);
                float4 v = *(const float4*)(x + e8 + 4);
                union { uint4 q; __half2 h[4]; } pk;
                pk.h[0] = __floats2half2_rn(u.x, u.y);
                pk.h[1] = __floats2half2_rn(u.z, u.w);
                pk.h[2] = __floats2half2_rn(v.x, v.y);
                pk.h[3] = __floats2half2_rn(v.z, v.w);
                *(uint4*)(xh + e8) = pk.q;
            }
        }
    }

    int nb = (b == NBUCK - 1) ? (NNODES - (NBUCK - 1) * 128) : 128;
    int eb0 = ebBase[l * NBUCK + b];
    int ecnt = bucketTotal[l * NBUCK + b];
    int csr0 = csrBase[l * NBUCK + b];
    const int* ebuf = edgeBuf + (size_t)l * NEDGES;
    int* srcsL = srcs + (size_t)l * (NEDGES + NNODES);
    if (t < 128) cnt[t] = 0;
    __syncthreads();
    for (int i = t; i < ecnt; i += 256)
        atomicAdd(&cnt[ebuf[eb0 + i] >> 17], 1);
    __syncthreads();
    if (t < 128) {
        int lane = t & 63;
        int x2 = cnt[t] + 1;
        #pragma unroll
        for (int o = 1; o < 64; o <<= 1) {
            int u = __shfl_up(x2, o);
            if (lane >= o) x2 += u;
        }
        offl[t] = x2;
    }
    __syncthreads();
    if (t < 128) {
        int c = cnt[t];
        int incl = offl[t] + ((t >= 64) ? offl[63] : 0);
        int o = csr0 + incl - (c + 1);
        cur[t] = o;
        if (t < nb) {
            int node = b * 128 + t;
            offs[l * NNODES + node] = o;
            deg[l * NNODES + node] = c;
            srcsL[o + c] = node;
        }
    }
    __syncthreads();
    for (int i = t; i < ecnt; i += 256) {
        int w = ebuf[eb0 + i];
        int pos = atomicAdd(&cur[w >> 17], 1);
        srcsL[pos] = w & 0x1FFFF;
    }
}

// ---------------- GEMM + attention logits via extended-N MFMA ----------------
// h16[M,128] = fp16(A @ B); aS[M,4]/aD[M,4] = src/dst logits per head.
// (x@W)·att == x·(W@att): appended columns 128..135 hold Wa = W @ att_masked.
// r8 configuration (grid 391, 256 rows/block, 4 iters, bfrag preload) — best
// measured. r9 (1563 blocks, inline-LDS): 900K bank conflicts, 439 total.
// r11 (782 blocks): 409 total. Per-block fixed cost (staging+Wa+preload)
// dominates; do NOT increase block count or drop the preload.

template <typename AT>
__global__ __launch_bounds__(256, 2) void gemm_mfma_k(const AT* __restrict__ A,
                                                      const float* __restrict__ B,
                                                      const float* __restrict__ attS,
                                                      const float* __restrict__ attD,
                                                      __half* __restrict__ C16,
                                                      float* __restrict__ aS,
                                                      float* __restrict__ aD, int M) {
    __shared__ __half Bt[144 * 136];  // Bt[n][k]; rows 128..135 Wa cols, 136..143 zero
    const int tid = threadIdx.x;
    {   // stage B transposed as fp16 (rows 0..127)
        int kk = (tid & 63) * 2;
        int g = tid >> 6;
        #pragma unroll
        for (int jn = 0; jn < 8; jn++) {
            int n0 = g * 4 + jn * 16;
            float4 r0 = *(const float4*)(B + (size_t)kk * 128 + n0);
            float4 r1 = *(const float4*)(B + (size_t)(kk + 1) * 128 + n0);
            float f0[4] = {r0.x, r0.y, r0.z, r0.w};
            float f1[4] = {r1.x, r1.y, r1.z, r1.w};
            #pragma unroll
            for (int i = 0; i < 4; i++)
                *(__half2*)(&Bt[(n0 + i) * 136 + kk]) = __floats2half2_rn(f0[i], f1[i]);
        }
    }
    if (tid < 128) {  // Wa columns (rows 128..135), fp32 accumulate
        int k = tid;
        const float* Brow = B + (size_t)k * 128;
        #pragma unroll
        for (int h = 0; h < NHEAD; h++) {
            float s0 = 0.f, s1 = 0.f;
            #pragma unroll 8
            for (int c = 0; c < 32; c++) {
                float bb = Brow[h * 32 + c];
                s0 += bb * attS[h * 32 + c];
                s1 += bb * attD[h * 32 + c];
            }
            Bt[(128 + h * 2 + 0) * 136 + k] = (_Float16)s0;
            Bt[(128 + h * 2 + 1) * 136 + k] = (_Float16)s1;
        }
    } else {
        int k = tid - 128;
        #pragma unroll
        for (int j = 8; j < 16; j++) Bt[(128 + j) * 136 + k] = (_Float16)0.f;
    }
    __syncthreads();

    const int lane = tid & 63;
    const int wave = tid >> 6;
    const int m = lane & 15;
    const int q = lane >> 4;

    half8 bfrag[9][4];
    #pragma unroll
    for (int c = 0; c < 9; c++)
        #pragma unroll
        for (int t = 0; t < 4; t++)
            bfrag[c][t] = *(const half8*)(&Bt[(c * 16 + m) * 136 + t * 32 + q * 8]);

    for (int iter = 0; iter < 4; iter++) {
        int rb = blockIdx.x * 256 + iter * 64 + wave * 16;  // wave-uniform
        if (rb >= M) break;
        int row = rb + m;
        int rowc = row < M ? row : M - 1;
        half8 a[4];
        if constexpr (std::is_same<AT, __half>::value) {
            const __half* ap = A + (size_t)rowc * HIDDIM;
            #pragma unroll
            for (int t = 0; t < 4; t++)
                a[t] = *(const half8*)(ap + t * 32 + q * 8);
        } else {
            const float* ap = A + (size_t)rowc * HIDDIM;
            #pragma unroll
            for (int t = 0; t < 4; t++) {
                float4 u = *(const float4*)(ap + t * 32 + q * 8);
                float4 v = *(const float4*)(ap + t * 32 + q * 8 + 4);
                half8 h;
                h[0] = (_Float16)u.x; h[1] = (_Float16)u.y;
                h[2] = (_Float16)u.z; h[3] = (_Float16)u.w;
                h[4] = (_Float16)v.x; h[5] = (_Float16)v.y;
                h[6] = (_Float16)v.z; h[7] = (_Float16)v.w;
                a[t] = h;
            }
        }
        floatx4 acc[9];
        #pragma unroll
        for (int c = 0; c < 9; c++) acc[c] = (floatx4){0.f, 0.f, 0.f, 0.f};
        #pragma unroll
        for (int t = 0; t < 4; t++)
            #pragma unroll
            for (int c = 0; c < 9; c++)
                acc[c] = __builtin_amdgcn_mfma_f32_16x16x32_f16(a[t], bfrag[c][t], acc[c], 0, 0, 0);
        #pragma unroll
        for (int c = 0; c < 8; c++)
            #pragma unroll
            for (int r = 0; r < 4; r++) {
                int grow = rb + q * 4 + r;
                if (grow < M)
                    C16[(size_t)grow * HIDDIM + c * 16 + m] = __float2half(acc[c][r]);
            }
        if (m < 8) {
            float* ap = (m & 1) ? aD : aS;
            int head = m >> 1;
            #pragma unroll
            for (int r = 0; r < 4; r++) {
                int grow = rb + q * 4 + r;
                if (grow < M) ap[(size_t)grow * 4 + head] = acc[8][r];
            }
        }
    }
}

// ---------------- aggregate: one 16-lane group per node, 2x 8-deep gather ----------------

template <bool HALF_OUT>
__global__ __launch_bounds__(256) void agg_k(const __half* __restrict__ h16,
                                             const int* __restrict__ offs,
                                             const int* __restrict__ deg,
                                             const int* __restrict__ srcs,
                                             const float* __restrict__ aS,
                                             const float* __restrict__ aD,
                                             const float* __restrict__ bias,
                                             void* __restrict__ outv) {
    int tid = threadIdx.x;
    int lane = tid & 63;
    int grp = lane >> 4;      // node group within wave (0..3)
    int cg = lane & 15;       // channel group within node
    int c8 = cg * 8;
    int head = cg >> 2;
    int n = blockIdx.x * 16 + (tid >> 6) * 4 + grp;
    bool nvalid = n < NNODES;
    int nn = nvalid ? n : NNODES - 1;
    int start = offs[nn];
    int cnt = deg[nn] + 1;
    float ad = aD[(size_t)nn * 4 + head];
    half2t acc0[4], acc1[4];
    #pragma unroll
    for (int i = 0; i < 4; i++) {
        acc0[i] = (half2t){(_Float16)0.f, (_Float16)0.f};
        acc1[i] = (half2t){(_Float16)0.f, (_Float16)0.f};
    }
    float wsum = 0.f;
    const int base = grp * 16;

    for (int chunk = 0; chunk < cnt; chunk += 16) {
        int idx = chunk + cg;
        int lim = cnt - chunk;  // edges beyond lim get weight 0
        int sv = srcs[start + (idx < cnt ? idx : cnt - 1)];  // clamped: always valid
        #pragma unroll
        for (int hblk = 0; hblk < 2; hblk++) {
            int jb = hblk * 8;
            if (jb >= lim) break;  // uniform within the 16-lane node group
            float asv[8];
            half8 hv[8];
            // issue all 8 edges' gathers up front — 8-deep MLP per lane
            #pragma unroll
            for (int j = 0; j < 8; j++) {
                int sj = __shfl(sv, base + jb + j);
                asv[j] = aS[(size_t)sj * 4 + head];
                hv[j] = *(const half8*)(h16 + (size_t)sj * HIDDIM + c8);
            }
            #pragma unroll
            for (int j = 0; j < 8; j++) {
                float e = asv[j] + ad;
                e = (e > 0.f) ? e : 0.2f * e;
                float w = (jb + j < lim) ? __expf(e) : 0.f;
                wsum += w;
                _Float16 wh = (_Float16)w;
                half2t w2 = (half2t){wh, wh};
                if (((jb + j) & 1) == 0) {
                    #pragma unroll
                    for (int i = 0; i < 4; i++)
                        acc0[i] += w2 * (half2t){hv[j][2 * i], hv[j][2 * i + 1]};
                } else {
                    #pragma unroll
                    for (int i = 0; i < 4; i++)
                        acc1[i] += w2 * (half2t){hv[j][2 * i], hv[j][2 * i + 1]};
                }
            }
        }
    }

    if (nvalid) {
        float inv = 1.f / (wsum + 1e-16f);
        float v[8];
        #pragma unroll
        for (int i = 0; i < 4; i++) {
            half2t s = acc0[i] + acc1[i];
            float o0 = (float)s[0] * inv + bias[c8 + 2 * i];
            float o1 = (float)s[1] * inv + bias[c8 + 2 * i + 1];
            v[2 * i] = o0 > 0.f ? o0 : 0.f;
            v[2 * i + 1] = o1 > 0.f ? o1 : 0.f;
        }
        if constexpr (HALF_OUT) {
            union { uint4 u; __half2 h2v[4]; } pk;
            #pragma unroll
            for (int i = 0; i < 4; i++) pk.h2v[i] = __floats2half2_rn(v[2 * i], v[2 * i + 1]);
            *(uint4*)((__half*)outv + (size_t)n * HIDDIM + c8) = pk.u;
        } else {
            float* out = (float*)outv;
            *(float4*)(out + (size_t)n * HIDDIM + c8) = make_float4(v[0], v[1], v[2], v[3]);
            *(float4*)(out + (size_t)n * HIDDIM + c8 + 4) = make_float4(v[4], v[5], v[6], v[7]);
        }
    }
}

// ---------------- launch ----------------

extern "C" void kernel_launch(void* const* d_in, const int* in_sizes, int n_in,
                              void* d_out, int out_size, void* d_ws, size_t ws_size,
                              hipStream_t stream) {
    (void)in_sizes; (void)n_in; (void)out_size; (void)ws_size;
    const float* x = (const float*)d_in[0];
    const int* e0 = (const int*)d_in[1];
    const int* e1 = (const int*)d_in[6];
    const int* e2 = (const int*)d_in[11];

    char* ws = (char*)d_ws;
    size_t off = 0;
    auto alloc = [&](size_t bytes) -> void* {
        void* p = ws + off;
        off += (bytes + 255) & ~(size_t)255;
        return p;
    };
    __half* xh      = (__half*)alloc((size_t)NNODES * HIDDIM * 2);
    __half* h16     = (__half*)alloc((size_t)NNODES * HIDDIM * 2);
    float* aS       = (float*)alloc((size_t)NNODES * 4 * 4);
    float* aD       = (float*)alloc((size_t)NNODES * 4 * 4);
    int* deg        = (int*)alloc((size_t)3 * NNODES * 4);
    int* offsArr    = (int*)alloc((size_t)3 * NNODES * 4);
    int* srcs       = (int*)alloc((size_t)3 * (NEDGES + NNODES) * 4);
    int* counts     = (int*)alloc((size_t)3 * NBLK * NBUCK * 4);
    int* bucketTot  = (int*)alloc((size_t)3 * NBUCK * 4);
    int* ebBase     = (int*)alloc((size_t)3 * NBUCK * 4);
    int* csrBase    = (int*)alloc((size_t)3 * NBUCK * 4);
    int* edgeBuf    = (int*)alloc((size_t)3 * NEDGES * 4);

    // CSR build for all 3 layers — no global atomics
    hipLaunchKernelGGL(bucketA_k, dim3(NBLK, 3), dim3(256), 0, stream, e0, e1, e2, counts);
    hipLaunchKernelGGL(bucketB1_k, dim3((NBUCK + 63) / 64, 3), dim3(256), 0, stream,
                       counts, bucketTot);
    hipLaunchKernelGGL(bucketB2_k, dim3(3), dim3(1024), 0, stream, bucketTot, ebBase, csrBase);
    hipLaunchKernelGGL(bucketC_k, dim3(NBLK, 3), dim3(256), 0, stream,
                       e0, e1, e2, counts, ebBase, edgeBuf);
    hipLaunchKernelGGL(bucketD_k, dim3(NBUCK, 3), dim3(256), 0, stream,
                       edgeBuf, bucketTot, ebBase, csrBase, offsArr, deg, srcs, x, xh);

    for (int l = 0; l < 3; l++) {
        const float* Wm    = (const float*)d_in[2 + 5 * l];
        const float* attS  = (const float*)d_in[3 + 5 * l];
        const float* attD  = (const float*)d_in[4 + 5 * l];
        const float* biasv = (const float*)d_in[5 + 5 * l];
        const int* offsL = offsArr + l * NNODES;
        const int* degL  = deg + l * NNODES;
        const int* srcsL = srcs + (size_t)l * (NEDGES + NNODES);

        hipLaunchKernelGGL((gemm_mfma_k<__half>), dim3((NNODES + 255) / 256), dim3(256), 0,
                           stream, xh, Wm, attS, attD, h16, aS, aD, NNODES);
        if (l == 2) {
            hipLaunchKernelGGL((agg_k<false>), dim3((NNODES + 15) / 16), dim3(256), 0, stream,
                               h16, offsL, degL, srcsL, aS, aD, biasv, d_out);
        } else {
            hipLaunchKernelGGL((agg_k<true>), dim3((NNODES + 15) / 16), dim3(256), 0, stream,
                               h16, offsL, degL, srcsL, aS, aD, biasv, (void*)xh);
        }
    }
}

// Round 13
// 377.396 us; speedup vs baseline: 1.1645x; 1.0286x over previous
//
#include <hip/hip_runtime.h>
#include <hip/hip_bf16.h>
#include <hip/hip_fp16.h>

#define NNODES 100000
#define NEDGES 800000
#define HIDDIM 128
#define NHEAD 4

// bucket sort parameters
#define EPB 2048                 // edges per chunk-block
#define NBLK 392                 // padded to 8*49 so XCD swizzle is exact; chunk 391 is empty
#define XCDG 49                  // NBLK / 8 — contiguous chunks per XCD
#define BSH 7                    // 128 nodes per bucket
#define NBUCK 782                // ceil(NNODES / 128); last bucket has 32 nodes

#define BT_ELEMS (144 * 136)     // staged-B image: 19584 halves = 39168 B = 2448 uint4

typedef _Float16 half8 __attribute__((ext_vector_type(8)));
typedef _Float16 half2t __attribute__((ext_vector_type(2)));
typedef float floatx4 __attribute__((ext_vector_type(4)));

// ---------------- B-image prep: once per layer (was replicated in every gemm block) ----
// Builds Bt[n][k] fp16 (rows 0..127 = B^T, rows 128..135 = Wa = W @ att, rows 136..143
// zero) with the exact op order the in-gemm staging used -> bit-identical numerics.

__global__ __launch_bounds__(256) void prepB_k(const float* __restrict__ W0,
                                               const float* __restrict__ aS0,
                                               const float* __restrict__ aD0,
                                               const float* __restrict__ W1,
                                               const float* __restrict__ aS1,
                                               const float* __restrict__ aD1,
                                               const float* __restrict__ W2,
                                               const float* __restrict__ aS2,
                                               const float* __restrict__ aD2,
                                               __half* __restrict__ BtAll) {
    int l = blockIdx.x;
    const float* B    = (l == 0) ? W0 : (l == 1) ? W1 : W2;
    const float* attS = (l == 0) ? aS0 : (l == 1) ? aS1 : aS2;
    const float* attD = (l == 0) ? aD0 : (l == 1) ? aD1 : aD2;
    __half* Bt = BtAll + (size_t)l * BT_ELEMS;
    const int tid = threadIdx.x;
    {   // B transposed as fp16 (rows 0..127)
        int kk = (tid & 63) * 2;
        int g = tid >> 6;
        #pragma unroll
        for (int jn = 0; jn < 8; jn++) {
            int n0 = g * 4 + jn * 16;
            float4 r0 = *(const float4*)(B + (size_t)kk * 128 + n0);
            float4 r1 = *(const float4*)(B + (size_t)(kk + 1) * 128 + n0);
            float f0[4] = {r0.x, r0.y, r0.z, r0.w};
            float f1[4] = {r1.x, r1.y, r1.z, r1.w};
            #pragma unroll
            for (int i = 0; i < 4; i++)
                *(__half2*)(&Bt[(n0 + i) * 136 + kk]) = __floats2half2_rn(f0[i], f1[i]);
        }
    }
    if (tid < 128) {  // Wa columns (rows 128..135), fp32 accumulate
        int k = tid;
        const float* Brow = B + (size_t)k * 128;
        #pragma unroll
        for (int h = 0; h < NHEAD; h++) {
            float s0 = 0.f, s1 = 0.f;
            #pragma unroll 8
            for (int c = 0; c < 32; c++) {
                float bb = Brow[h * 32 + c];
                s0 += bb * attS[h * 32 + c];
                s1 += bb * attD[h * 32 + c];
            }
            Bt[(128 + h * 2 + 0) * 136 + k] = (_Float16)s0;
            Bt[(128 + h * 2 + 1) * 136 + k] = (_Float16)s1;
        }
    } else {
        int k = tid - 128;
        #pragma unroll
        for (int j = 8; j < 16; j++) Bt[(128 + j) * 136 + k] = (_Float16)0.f;
    }
}

// ---------------- CSR build via bucket counting-sort (no global atomics) ----------------

__global__ __launch_bounds__(256) void bucketA_k(const int* __restrict__ e0,
                                                 const int* __restrict__ e1,
                                                 const int* __restrict__ e2,
                                                 int* __restrict__ counts) {
    __shared__ int hist[NBUCK];
    int l = blockIdx.y;
    const int* dst = ((l == 0) ? e0 : (l == 1) ? e1 : e2) + NEDGES;
    int j = blockIdx.x;
    for (int t = threadIdx.x; t < NBUCK; t += 256) hist[t] = 0;
    __syncthreads();
    int base = j * EPB;
    int lim = min(EPB, NEDGES - base);
    if (lim == EPB) {
        #pragma unroll
        for (int it = 0; it < EPB / 256; it++)
            atomicAdd(&hist[dst[base + it * 256 + threadIdx.x] >> BSH], 1);
    } else {
        for (int i = threadIdx.x; i < lim; i += 256)
            atomicAdd(&hist[dst[base + i] >> BSH], 1);
    }
    __syncthreads();
    int* crow = counts + ((size_t)l * NBLK + j) * NBUCK;
    for (int t = threadIdx.x; t < NBUCK; t += 256) crow[t] = hist[t];
}

__global__ __launch_bounds__(256) void bucketB1_k(int* __restrict__ counts,
                                                  int* __restrict__ bucketTotal) {
    __shared__ int part[4][64];
    int l = blockIdx.y;
    int tid = threadIdx.x;
    int wave = tid >> 6;
    int lane = tid & 63;
    int b = blockIdx.x * 64 + lane;
    bool valid = b < NBUCK;
    const int CQ = NBLK / 4;
    int t0 = wave * CQ, t1 = t0 + CQ;
    int sum = 0;
    if (valid) {
        for (int t = t0; t < t1; t++)
            sum += counts[((size_t)l * NBLK + t) * NBUCK + b];
    }
    part[wave][lane] = sum;
    __syncthreads();
    int off = 0;
    for (int w = 0; w < wave; w++) off += part[w][lane];
    if (valid) {
        int run = off;
        for (int t = t0; t < t1; t++) {
            size_t idx = ((size_t)l * NBLK + t) * NBUCK + b;
            int v = counts[idx];
            counts[idx] = run;
            run += v;
        }
        if (wave == 3) bucketTotal[l * NBUCK + b] = run;
    }
}

__global__ __launch_bounds__(1024) void bucketB2_k(const int* __restrict__ bucketTotal,
                                                   int* __restrict__ ebBase,
                                                   int* __restrict__ csrBase) {
    __shared__ int sd[1024];
    int l = blockIdx.x;
    int t = threadIdx.x;
    int tot = (t < NBUCK) ? bucketTotal[l * NBUCK + t] : 0;
    sd[t] = tot;
    __syncthreads();
    for (int off = 1; off < 1024; off <<= 1) {
        int u = (t >= off) ? sd[t - off] : 0;
        __syncthreads();
        sd[t] += u;
        __syncthreads();
    }
    if (t < NBUCK) ebBase[l * NBUCK + t] = sd[t] - tot;
    __syncthreads();
    int nb = (t == NBUCK - 1) ? (NNODES - (NBUCK - 1) * 128) : 128;
    int v2 = (t < NBUCK) ? (tot + nb) : 0;
    sd[t] = v2;
    __syncthreads();
    for (int off = 1; off < 1024; off <<= 1) {
        int u = (t >= off) ? sd[t - off] : 0;
        __syncthreads();
        sd[t] += u;
        __syncthreads();
    }
    if (t < NBUCK) csrBase[l * NBUCK + t] = sd[t] - v2;
}

__global__ __launch_bounds__(256) void bucketC_k(const int* __restrict__ e0,
                                                 const int* __restrict__ e1,
                                                 const int* __restrict__ e2,
                                                 const int* __restrict__ counts,
                                                 const int* __restrict__ ebBase,
                                                 int* __restrict__ edgeBuf) {
    __shared__ int cur[NBUCK];
    int l = blockIdx.y;
    const int* ei = (l == 0) ? e0 : (l == 1) ? e1 : e2;
    const int* src = ei;
    const int* dst = ei + NEDGES;
    int bx = blockIdx.x;
    int j = (bx & 7) * XCDG + (bx >> 3);
    const int* bs = counts + ((size_t)l * NBLK + j) * NBUCK;
    const int* eb = ebBase + l * NBUCK;
    for (int t = threadIdx.x; t < NBUCK; t += 256) cur[t] = eb[t] + bs[t];
    __syncthreads();
    int base = j * EPB;
    int lim = min(EPB, NEDGES - base);
    int* ebuf = edgeBuf + (size_t)l * NEDGES;
    if (lim == EPB) {
        #pragma unroll
        for (int it = 0; it < EPB / 256; it++) {
            int i = it * 256 + threadIdx.x;
            int d = dst[base + i];
            int s = src[base + i];
            int pos = atomicAdd(&cur[d >> BSH], 1);
            ebuf[pos] = ((d & 127) << 17) | s;
        }
    } else {
        for (int i = threadIdx.x; i < lim; i += 256) {
            int d = dst[base + i];
            int s = src[base + i];
            int pos = atomicAdd(&cur[d >> BSH], 1);
            ebuf[pos] = ((d & 127) << 17) | s;
        }
    }
}

// Phase D: per-bucket CSR finalize. Layer-0 blocks also convert x -> fp16
// (coalesced, overlapped with the latency-bound LDS-atomic scatter).
__global__ __launch_bounds__(256) void bucketD_k(const int* __restrict__ edgeBuf,
                                                 const int* __restrict__ bucketTotal,
                                                 const int* __restrict__ ebBase,
                                                 const int* __restrict__ csrBase,
                                                 int* __restrict__ offs,
                                                 int* __restrict__ deg,
                                                 int* __restrict__ srcs,
                                                 const float* __restrict__ x,
                                                 __half* __restrict__ xh) {
    __shared__ int cnt[128];
    __shared__ int offl[128];
    __shared__ int cur[128];
    int b = blockIdx.x, l = blockIdx.y;
    int t = threadIdx.x;

    if (l == 0) {
        // fused x -> fp16 conversion: 16384 elems/block, float4x2 -> uint4
        const size_t T = (size_t)NNODES * HIDDIM;  // 12.8M, multiple of 8
        size_t base = (size_t)b * 16384;
        #pragma unroll
        for (int i = 0; i < 8; i++) {
            size_t e8 = base + ((size_t)i * 256 + t) * 8;
            if (e8 < T) {
                float4 u = *(const float4*)(x + e8);
                float4 v = *(const float4*)(x + e8 + 4);
                union { uint4 q; __half2 h[4]; } pk;
                pk.h[0] = __floats2half2_rn(u.x, u.y);
                pk.h[1] = __floats2half2_rn(u.z, u.w);
                pk.h[2] = __floats2half2_rn(v.x, v.y);
                pk.h[3] = __floats2half2_rn(v.z, v.w);
                *(uint4*)(xh + e8) = pk.q;
            }
        }
    }

    int nb = (b == NBUCK - 1) ? (NNODES - (NBUCK - 1) * 128) : 128;
    int eb0 = ebBase[l * NBUCK + b];
    int ecnt = bucketTotal[l * NBUCK + b];
    int csr0 = csrBase[l * NBUCK + b];
    const int* ebuf = edgeBuf + (size_t)l * NEDGES;
    int* srcsL = srcs + (size_t)l * (NEDGES + NNODES);
    if (t < 128) cnt[t] = 0;
    __syncthreads();
    for (int i = t; i < ecnt; i += 256)
        atomicAdd(&cnt[ebuf[eb0 + i] >> 17], 1);
    __syncthreads();
    if (t < 128) {
        int lane = t & 63;
        int x2 = cnt[t] + 1;
        #pragma unroll
        for (int o = 1; o < 64; o <<= 1) {
            int u = __shfl_up(x2, o);
            if (lane >= o) x2 += u;
        }
        offl[t] = x2;
    }
    __syncthreads();
    if (t < 128) {
        int c = cnt[t];
        int incl = offl[t] + ((t >= 64) ? offl[63] : 0);
        int o = csr0 + incl - (c + 1);
        cur[t] = o;
        if (t < nb) {
            int node = b * 128 + t;
            offs[l * NNODES + node] = o;
            deg[l * NNODES + node] = c;
            srcsL[o + c] = node;
        }
    }
    __syncthreads();
    for (int i = t; i < ecnt; i += 256) {
        int w = ebuf[eb0 + i];
        int pos = atomicAdd(&cur[w >> 17], 1);
        srcsL[pos] = w & 0x1FFFF;
    }
}

// ---------------- GEMM + attention logits via extended-N MFMA ----------------
// h16[M,128] = fp16(A @ B); aS[M,4]/aD[M,4] = src/dst logits per head.
// r8 grid shape (391 blocks, 256 rows, 4 iters, bfrag preload) — best measured.
// Staging is now a flat coalesced uint4 copy of the precomputed 39KB Bt image
// (prepB_k), removing the replicated transpose/convert/Wa fixed cost that r9/r11
// proved dominant. Numerics identical (image built with the same op order).

__global__ __launch_bounds__(256, 2) void gemm_mfma_k(const __half* __restrict__ A,
                                                      const __half* __restrict__ Btg,
                                                      __half* __restrict__ C16,
                                                      float* __restrict__ aS,
                                                      float* __restrict__ aD, int M) {
    __shared__ uint4 BtU[BT_ELEMS / 8];  // 2448 uint4, 16B-aligned
    const __half* Bt = (const __half*)BtU;
    const int tid = threadIdx.x;
    {   // flat coalesced copy: 2448 uint4 over 256 threads
        const uint4* src = (const uint4*)Btg;
        #pragma unroll
        for (int i = 0; i < 9; i++) BtU[i * 256 + tid] = src[i * 256 + tid];
        int r = 9 * 256 + tid;
        if (r < BT_ELEMS / 8) BtU[r] = src[r];
    }
    __syncthreads();

    const int lane = tid & 63;
    const int wave = tid >> 6;
    const int m = lane & 15;
    const int q = lane >> 4;

    half8 bfrag[9][4];
    #pragma unroll
    for (int c = 0; c < 9; c++)
        #pragma unroll
        for (int t = 0; t < 4; t++)
            bfrag[c][t] = *(const half8*)(&Bt[(c * 16 + m) * 136 + t * 32 + q * 8]);

    for (int iter = 0; iter < 4; iter++) {
        int rb = blockIdx.x * 256 + iter * 64 + wave * 16;  // wave-uniform
        if (rb >= M) break;
        int row = rb + m;
        int rowc = row < M ? row : M - 1;
        half8 a[4];
        {
            const __half* ap = A + (size_t)rowc * HIDDIM;
            #pragma unroll
            for (int t = 0; t < 4; t++)
                a[t] = *(const half8*)(ap + t * 32 + q * 8);
        }
        floatx4 acc[9];
        #pragma unroll
        for (int c = 0; c < 9; c++) acc[c] = (floatx4){0.f, 0.f, 0.f, 0.f};
        #pragma unroll
        for (int t = 0; t < 4; t++)
            #pragma unroll
            for (int c = 0; c < 9; c++)
                acc[c] = __builtin_amdgcn_mfma_f32_16x16x32_f16(a[t], bfrag[c][t], acc[c], 0, 0, 0);
        #pragma unroll
        for (int c = 0; c < 8; c++)
            #pragma unroll
            for (int r = 0; r < 4; r++) {
                int grow = rb + q * 4 + r;
                if (grow < M)
                    C16[(size_t)grow * HIDDIM + c * 16 + m] = __float2half(acc[c][r]);
            }
        if (m < 8) {
            float* ap = (m & 1) ? aD : aS;
            int head = m >> 1;
            #pragma unroll
            for (int r = 0; r < 4; r++) {
                int grow = rb + q * 4 + r;
                if (grow < M) ap[(size_t)grow * 4 + head] = acc[8][r];
            }
        }
    }
}

// ---------------- aggregate: one 16-lane group per node, 2x 8-deep gather ----------------

template <bool HALF_OUT>
__global__ __launch_bounds__(256) void agg_k(const __half* __restrict__ h16,
                                             const int* __restrict__ offs,
                                             const int* __restrict__ deg,
                                             const int* __restrict__ srcs,
                                             const float* __restrict__ aS,
                                             const float* __restrict__ aD,
                                             const float* __restrict__ bias,
                                             void* __restrict__ outv) {
    int tid = threadIdx.x;
    int lane = tid & 63;
    int grp = lane >> 4;      // node group within wave (0..3)
    int cg = lane & 15;       // channel group within node
    int c8 = cg * 8;
    int head = cg >> 2;
    int n = blockIdx.x * 16 + (tid >> 6) * 4 + grp;
    bool nvalid = n < NNODES;
    int nn = nvalid ? n : NNODES - 1;
    int start = offs[nn];
    int cnt = deg[nn] + 1;
    float ad = aD[(size_t)nn * 4 + head];
    half2t acc0[4], acc1[4];
    #pragma unroll
    for (int i = 0; i < 4; i++) {
        acc0[i] = (half2t){(_Float16)0.f, (_Float16)0.f};
        acc1[i] = (half2t){(_Float16)0.f, (_Float16)0.f};
    }
    float wsum = 0.f;
    const int base = grp * 16;

    for (int chunk = 0; chunk < cnt; chunk += 16) {
        int idx = chunk + cg;
        int lim = cnt - chunk;  // edges beyond lim get weight 0
        int sv = srcs[start + (idx < cnt ? idx : cnt - 1)];  // clamped: always valid
        #pragma unroll
        for (int hblk = 0; hblk < 2; hblk++) {
            int jb = hblk * 8;
            if (jb >= lim) break;  // uniform within the 16-lane node group
            float asv[8];
            half8 hv[8];
            // issue all 8 edges' gathers up front — 8-deep MLP per lane
            #pragma unroll
            for (int j = 0; j < 8; j++) {
                int sj = __shfl(sv, base + jb + j);
                asv[j] = aS[(size_t)sj * 4 + head];
                hv[j] = *(const half8*)(h16 + (size_t)sj * HIDDIM + c8);
            }
            #pragma unroll
            for (int j = 0; j < 8; j++) {
                float e = asv[j] + ad;
                e = (e > 0.f) ? e : 0.2f * e;
                float w = (jb + j < lim) ? __expf(e) : 0.f;
                wsum += w;
                _Float16 wh = (_Float16)w;
                half2t w2 = (half2t){wh, wh};
                if (((jb + j) & 1) == 0) {
                    #pragma unroll
                    for (int i = 0; i < 4; i++)
                        acc0[i] += w2 * (half2t){hv[j][2 * i], hv[j][2 * i + 1]};
                } else {
                    #pragma unroll
                    for (int i = 0; i < 4; i++)
                        acc1[i] += w2 * (half2t){hv[j][2 * i], hv[j][2 * i + 1]};
                }
            }
        }
    }

    if (nvalid) {
        float inv = 1.f / (wsum + 1e-16f);
        float v[8];
        #pragma unroll
        for (int i = 0; i < 4; i++) {
            half2t s = acc0[i] + acc1[i];
            float o0 = (float)s[0] * inv + bias[c8 + 2 * i];
            float o1 = (float)s[1] * inv + bias[c8 + 2 * i + 1];
            v[2 * i] = o0 > 0.f ? o0 : 0.f;
            v[2 * i + 1] = o1 > 0.f ? o1 : 0.f;
        }
        if constexpr (HALF_OUT) {
            union { uint4 u; __half2 h2v[4]; } pk;
            #pragma unroll
            for (int i = 0; i < 4; i++) pk.h2v[i] = __floats2half2_rn(v[2 * i], v[2 * i + 1]);
            *(uint4*)((__half*)outv + (size_t)n * HIDDIM + c8) = pk.u;
        } else {
            float* out = (float*)outv;
            *(float4*)(out + (size_t)n * HIDDIM + c8) = make_float4(v[0], v[1], v[2], v[3]);
            *(float4*)(out + (size_t)n * HIDDIM + c8 + 4) = make_float4(v[4], v[5], v[6], v[7]);
        }
    }
}

// ---------------- launch ----------------

extern "C" void kernel_launch(void* const* d_in, const int* in_sizes, int n_in,
                              void* d_out, int out_size, void* d_ws, size_t ws_size,
                              hipStream_t stream) {
    (void)in_sizes; (void)n_in; (void)out_size; (void)ws_size;
    const float* x = (const float*)d_in[0];
    const int* e0 = (const int*)d_in[1];
    const int* e1 = (const int*)d_in[6];
    const int* e2 = (const int*)d_in[11];

    char* ws = (char*)d_ws;
    size_t off = 0;
    auto alloc = [&](size_t bytes) -> void* {
        void* p = ws + off;
        off += (bytes + 255) & ~(size_t)255;
        return p;
    };
    __half* xh      = (__half*)alloc((size_t)NNODES * HIDDIM * 2);
    __half* h16     = (__half*)alloc((size_t)NNODES * HIDDIM * 2);
    __half* BtAll   = (__half*)alloc((size_t)3 * BT_ELEMS * 2);
    float* aS       = (float*)alloc((size_t)NNODES * 4 * 4);
    float* aD       = (float*)alloc((size_t)NNODES * 4 * 4);
    int* deg        = (int*)alloc((size_t)3 * NNODES * 4);
    int* offsArr    = (int*)alloc((size_t)3 * NNODES * 4);
    int* srcs       = (int*)alloc((size_t)3 * (NEDGES + NNODES) * 4);
    int* counts     = (int*)alloc((size_t)3 * NBLK * NBUCK * 4);
    int* bucketTot  = (int*)alloc((size_t)3 * NBUCK * 4);
    int* ebBase     = (int*)alloc((size_t)3 * NBUCK * 4);
    int* csrBase    = (int*)alloc((size_t)3 * NBUCK * 4);
    int* edgeBuf    = (int*)alloc((size_t)3 * NEDGES * 4);

    // one-time B-image prep (3 blocks) + CSR build for all 3 layers
    hipLaunchKernelGGL(prepB_k, dim3(3), dim3(256), 0, stream,
                       (const float*)d_in[2], (const float*)d_in[3], (const float*)d_in[4],
                       (const float*)d_in[7], (const float*)d_in[8], (const float*)d_in[9],
                       (const float*)d_in[12], (const float*)d_in[13], (const float*)d_in[14],
                       BtAll);
    hipLaunchKernelGGL(bucketA_k, dim3(NBLK, 3), dim3(256), 0, stream, e0, e1, e2, counts);
    hipLaunchKernelGGL(bucketB1_k, dim3((NBUCK + 63) / 64, 3), dim3(256), 0, stream,
                       counts, bucketTot);
    hipLaunchKernelGGL(bucketB2_k, dim3(3), dim3(1024), 0, stream, bucketTot, ebBase, csrBase);
    hipLaunchKernelGGL(bucketC_k, dim3(NBLK, 3), dim3(256), 0, stream,
                       e0, e1, e2, counts, ebBase, edgeBuf);
    hipLaunchKernelGGL(bucketD_k, dim3(NBUCK, 3), dim3(256), 0, stream,
                       edgeBuf, bucketTot, ebBase, csrBase, offsArr, deg, srcs, x, xh);

    for (int l = 0; l < 3; l++) {
        const float* biasv = (const float*)d_in[5 + 5 * l];
        const int* offsL = offsArr + l * NNODES;
        const int* degL  = deg + l * NNODES;
        const int* srcsL = srcs + (size_t)l * (NEDGES + NNODES);

        hipLaunchKernelGGL(gemm_mfma_k, dim3((NNODES + 255) / 256), dim3(256), 0,
                           stream, xh, BtAll + (size_t)l * BT_ELEMS, h16, aS, aD, NNODES);
        if (l == 2) {
            hipLaunchKernelGGL((agg_k<false>), dim3((NNODES + 15) / 16), dim3(256), 0, stream,
                               h16, offsL, degL, srcsL, aS, aD, biasv, d_out);
        } else {
            hipLaunchKernelGGL((agg_k<true>), dim3((NNODES + 15) / 16), dim3(256), 0, stream,
                               h16, offsL, degL, srcsL, aS, aD, biasv, (void*)xh);
        }
    }
}